// Round 5
// baseline (837.952 us; speedup 1.0000x reference)
//
#include <hip/hip_runtime.h>

#define BB 16
#define NN 4096
#define NPOINTS 1024
#define KK 32
#define NPTS (BB*NPOINTS)        // 16384
#define NWN  (BB*NPOINTS*KK)     // 524288
#define EPSF 1e-5f
#define NSLOT 16

typedef unsigned short u16;
typedef u16  u16x8 __attribute__((ext_vector_type(8)));
typedef short s16x8 __attribute__((ext_vector_type(8)));
typedef float f32x4 __attribute__((ext_vector_type(4)));

__device__ __forceinline__ float bf(u16 u){
  union { unsigned int i; float f; } v; v.i = ((unsigned int)u) << 16; return v.f;
}
__device__ __forceinline__ u16 f2b(float f){
  union { float ff; unsigned int i; } v; v.ff = f;
  unsigned int r = v.i + 0x7FFFu + ((v.i >> 16) & 1u);
  return (u16)(r >> 16);
}
__device__ __forceinline__ void wave_red2(float& s, float& q){
  #pragma unroll
  for (int m = 1; m < 64; m <<= 1){ s += __shfl_xor(s, m); q += __shfl_xor(q, m); }
}

// ---------------- K0: new_xyz gather (f32 copy) ----------------
__global__ __launch_bounds__(256) void k_newxyz(const float* xyz, const int* didx, float* out){
  int p = blockIdx.x * 256 + threadIdx.x;
  if (p >= NPTS) return;
  int b = p >> 10;
  int idx = didx[p];
  const float* src = xyz + ((size_t)(b * NN + idx)) * 3;
  float* dst = out + (size_t)p * 3;
  dst[0] = src[0]; dst[1] = src[1]; dst[2] = src[2];
}

// ---------------- k_prep: lwbt[o][ch] = bf16(lw[ch][o])  (o-major for MFMA B-frags) ----------------
__global__ __launch_bounds__(256) void k_prep(const float* lw, u16* lwbt){
  __shared__ float T[64][65];
  int t = threadIdx.x;
  int kb = blockIdx.x * 64;
  {
    int k = t >> 2, c4 = t & 3;
    #pragma unroll
    for (int j = 0; j < 4; ++j)
      *(f32x4*)&T[k][c4*16 + j*4] = *(const f32x4*)(lw + (size_t)(kb + k)*64 + c4*16 + j*4);
  }
  __syncthreads();
  {
    int n = t >> 2, k4 = t & 3;
    u16x8 o0, o1;
    #pragma unroll
    for (int j = 0; j < 8; ++j) o0[j] = f2b(T[k4*16 + j][n]);
    #pragma unroll
    for (int j = 0; j < 8; ++j) o1[j] = f2b(T[k4*16 + 8 + j][n]);
    *(u16x8*)(lwbt + (size_t)n*4096 + kb + k4*16)     = o0;
    *(u16x8*)(lwbt + (size_t)n*4096 + kb + k4*16 + 8) = o1;
  }
}

// ---------------- stats kernels: 256 blocks, partial write (no atomics) ----------------
__global__ __launch_bounds__(256) void k_wn0(const float* lc, const float* w0, const float* b0, float* P0){
  __shared__ float w0c[48], b0c[16];
  __shared__ float shs[4][16], shq[4][16];
  int t = threadIdx.x;
  if (t < 48) w0c[t] = w0[t];
  if (t < 16) b0c[t] = b0[t];
  __syncthreads();
  float s[16], q[16];
  #pragma unroll
  for (int oc = 0; oc < 16; ++oc){ s[oc] = 0.f; q[oc] = 0.f; }
  size_t base = (size_t)blockIdx.x * 2048 + t;
  for (int i = 0; i < 8; ++i){
    size_t p = base + (size_t)i * 256;
    float x0 = lc[p*3+0], x1 = lc[p*3+1], x2 = lc[p*3+2];
    #pragma unroll
    for (int oc = 0; oc < 16; ++oc){
      float y = w0c[oc*3]*x0 + w0c[oc*3+1]*x1 + w0c[oc*3+2]*x2 + b0c[oc];
      s[oc] += y; q[oc] += y*y;
    }
  }
  int lane = t & 63, wid = t >> 6;
  #pragma unroll
  for (int oc = 0; oc < 16; ++oc){
    wave_red2(s[oc], q[oc]);
    if (lane == 0){ shs[wid][oc] = s[oc]; shq[wid][oc] = q[oc]; }
  }
  __syncthreads();
  if (t < 16){
    P0[blockIdx.x*32 + t]      = shs[0][t] + shs[1][t] + shs[2][t] + shs[3][t];
    P0[blockIdx.x*32 + 16 + t] = shq[0][t] + shq[1][t] + shq[2][t] + shq[3][t];
  }
}

__global__ __launch_bounds__(256) void k_wn1(const float* lc, const float* w0, const float* b0,
                                             const float* g0, const float* be0, const float* S0,
                                             const float* w1, const float* b1, float* P1){
  __shared__ float w0c[48], b0c[16], a0[16], d0[16], w1c[256], b1c[16];
  __shared__ float shs[4][16], shq[4][16];
  int t = threadIdx.x;
  if (t < 48) w0c[t] = w0[t];
  if (t < 16){
    b0c[t] = b0[t]; b1c[t] = b1[t];
    float m = S0[t] * (1.0f/NWN);
    float v = S0[16+t] * (1.0f/NWN) - m*m;
    float a = g0[t] * rsqrtf(v + EPSF);
    a0[t] = a; d0[t] = be0[t] - m*a;
  }
  w1c[t] = w1[t];
  __syncthreads();
  float s[16], q[16];
  #pragma unroll
  for (int oc = 0; oc < 16; ++oc){ s[oc] = 0.f; q[oc] = 0.f; }
  size_t base = (size_t)blockIdx.x * 2048 + t;
  for (int i = 0; i < 8; ++i){
    size_t p = base + (size_t)i * 256;
    float x0 = lc[p*3+0], x1 = lc[p*3+1], x2 = lc[p*3+2];
    float h0[16];
    #pragma unroll
    for (int oc = 0; oc < 16; ++oc){
      float y = w0c[oc*3]*x0 + w0c[oc*3+1]*x1 + w0c[oc*3+2]*x2 + b0c[oc];
      h0[oc] = fmaxf(0.f, a0[oc]*y + d0[oc]);
    }
    #pragma unroll
    for (int oc = 0; oc < 16; ++oc){
      float y = b1c[oc];
      #pragma unroll
      for (int ic = 0; ic < 16; ++ic) y += w1c[oc*16+ic]*h0[ic];
      s[oc] += y; q[oc] += y*y;
    }
  }
  int lane = t & 63, wid = t >> 6;
  #pragma unroll
  for (int oc = 0; oc < 16; ++oc){
    wave_red2(s[oc], q[oc]);
    if (lane == 0){ shs[wid][oc] = s[oc]; shq[wid][oc] = q[oc]; }
  }
  __syncthreads();
  if (t < 16){
    P1[blockIdx.x*32 + t]      = shs[0][t] + shs[1][t] + shs[2][t] + shs[3][t];
    P1[blockIdx.x*32 + 16 + t] = shq[0][t] + shq[1][t] + shq[2][t] + shq[3][t];
  }
}

__global__ __launch_bounds__(256) void k_wn2(const float* lc,
    const float* w0, const float* b0, const float* g0, const float* be0, const float* S0,
    const float* w1, const float* b1, const float* g1, const float* be1, const float* S1,
    const float* w2, const float* b2, float* P2){
  __shared__ float w0c[48], b0c[16], a0[16], d0[16];
  __shared__ float w1c[256], b1c[16], a1[16], d1[16];
  __shared__ float w2c[64][17], b2c[64];
  __shared__ float h0s[64][17], h1s[64][17];
  __shared__ float shs[4][64], shq[4][64];
  int t = threadIdx.x;
  if (t < 48) w0c[t] = w0[t];
  if (t < 16){
    b0c[t] = b0[t]; b1c[t] = b1[t];
    float m = S0[t] * (1.0f/NWN);
    float v = S0[16+t] * (1.0f/NWN) - m*m;
    float a = g0[t] * rsqrtf(v + EPSF);
    a0[t] = a; d0[t] = be0[t] - m*a;
    float m1 = S1[t] * (1.0f/NWN);
    float v1 = S1[16+t] * (1.0f/NWN) - m1*m1;
    float aa = g1[t] * rsqrtf(v1 + EPSF);
    a1[t] = aa; d1[t] = be1[t] - m1*aa;
  }
  w1c[t] = w1[t];
  for (int i = t; i < 1024; i += 256) w2c[i>>4][i&15] = w2[i];
  if (t < 64) b2c[t] = b2[t];
  __syncthreads();
  int oc = t & 63, w = t >> 6;
  float s = 0.f, q = 0.f;
  size_t cbase = (size_t)blockIdx.x * 2048;
  for (int ch = 0; ch < 32; ++ch){
    size_t pbase = cbase + ch * 64;
    __syncthreads();
    #pragma unroll
    for (int j = 0; j < 4; ++j){
      int l = t + j * 256;
      int k = l >> 4, c = l & 15;
      const float* xp = lc + (pbase + k) * 3;
      float y = w0c[c*3]*xp[0] + w0c[c*3+1]*xp[1] + w0c[c*3+2]*xp[2] + b0c[c];
      h0s[k][c] = fmaxf(0.f, a0[c]*y + d0[c]);
    }
    __syncthreads();
    #pragma unroll
    for (int j = 0; j < 4; ++j){
      int l = t + j * 256;
      int k = l >> 4, c = l & 15;
      float y = b1c[c];
      #pragma unroll
      for (int ic = 0; ic < 16; ++ic) y += w1c[c*16+ic] * h0s[k][ic];
      h1s[k][c] = fmaxf(0.f, a1[c]*y + d1[c]);
    }
    __syncthreads();
    #pragma unroll
    for (int kk = 0; kk < 16; ++kk){
      int k = w * 16 + kk;
      float y = b2c[oc];
      #pragma unroll
      for (int ic = 0; ic < 16; ++ic) y += w2c[oc][ic] * h1s[k][ic];
      s += y; q += y*y;
    }
  }
  shs[w][oc] = s; shq[w][oc] = q;
  __syncthreads();
  if (t < 64){
    P2[blockIdx.x*128 + t]      = shs[0][t] + shs[1][t] + shs[2][t] + shs[3][t];
    P2[blockIdx.x*128 + 64 + t] = shq[0][t] + shq[1][t] + shq[2][t] + shq[3][t];
  }
}

// ---------------- generic partial reduce ----------------
__global__ __launch_bounds__(256) void k_redP(const float* P, float* S, int nch){
  int t = threadIdx.x;
  if (t >= nch) return;
  float s = 0.f;
  for (int r = 0; r < 256; ++r) s += P[r*nch + t];
  S[t] = s;
}

// ---------------- K5: main pass — gather + WeightNet + per-point MFMA matmul ----------------
__global__ __launch_bounds__(256) void k_main(const float* lcg, const int* nbrg,
    const float* points, const float* xyz,
    const float* w0, const float* b0, const float* g0, const float* be0, const float* S0,
    const float* w1, const float* b1, const float* g1, const float* be1, const float* S1,
    const float* w2, const float* b2, const float* g2, const float* be2, const float* S2,
    u16* npw, float* slotC){
  __shared__ float Gf[32*68];          // gather staging, f32, row k, stride 68
  __shared__ u16   Gt[64*40];          // bf16 K-major: Gt[i][k], stride 40
  __shared__ u16   Wt[64*40];          // bf16 K-major: Wt[o][k], stride 40
  __shared__ float H0s[32][17];
  __shared__ float H1s[32][20];        // stride 20 -> 16B-aligned f32x4 rows
  __shared__ u16   Cl[64*72];          // bf16 C staging, stride 72
  __shared__ float lcs[32][4];
  __shared__ int   nbr[32];
  __shared__ float w0c[48], b0c[16], a0c[16], d0c[16];
  __shared__ float w1c[16][17], b1c[16], a1c[16], d1c[16];
  __shared__ float w2c[64][17], b2c[64], a2c[64], d2c[64];
  int t = threadIdx.x;
  if (t < 48) w0c[t] = w0[t];
  if (t < 16){
    b0c[t] = b0[t]; b1c[t] = b1[t];
    float m = S0[t] * (1.0f/NWN);
    float v = S0[16+t] * (1.0f/NWN) - m*m;
    float a = g0[t] * rsqrtf(v + EPSF);
    a0c[t] = a; d0c[t] = be0[t] - m*a;
    float m1 = S1[t] * (1.0f/NWN);
    float v1 = S1[16+t] * (1.0f/NWN) - m1*m1;
    float aa = g1[t] * rsqrtf(v1 + EPSF);
    a1c[t] = aa; d1c[t] = be1[t] - m1*aa;
  }
  w1c[t>>4][t&15] = w1[t];
  for (int i = t; i < 1024; i += 256) w2c[i>>4][i&15] = w2[i];
  if (t < 64){
    b2c[t] = b2[t];
    float m = S2[t] * (1.0f/NWN);
    float v = S2[64+t] * (1.0f/NWN) - m*m;
    float a = g2[t] * rsqrtf(v + EPSF);
    a2c[t] = a; d2c[t] = be2[t] - m*a;
  }
  int w = t >> 6, l = t & 63;
  float s[16], q[16];
  #pragma unroll
  for (int j = 0; j < 16; ++j){ s[j] = 0.f; q[j] = 0.f; }

  for (int p = 0; p < 16; ++p){
    int point = blockIdx.x * 16 + p;
    int bb = point >> 10;
    __syncthreads();   // (A) previous point's LDS reads complete
    if (t < 32) nbr[t] = nbrg[(size_t)point * 32 + t];
    if (t < 96){ int k = t / 3, c = t % 3; lcs[k][c] = lcg[(size_t)point * 96 + t]; }
    __syncthreads();   // (B)
    // gather grouped -> Gf f32 (coalesced row writes)
    {
      int k = t >> 3, c8 = t & 7;
      int n = nbr[k];
      const float* prow = points + (size_t)(bb * NN + n) * 61;
      const float* xr   = xyz    + (size_t)(bb * NN + n) * 3;
      float v[8];
      #pragma unroll
      for (int j = 0; j < 8; ++j){
        int c = c8 * 8 + j;
        v[j] = (c < 61) ? prow[c] : xr[c - 61];
      }
      f32x4 lo = {v[0],v[1],v[2],v[3]}, hi = {v[4],v[5],v[6],v[7]};
      *(f32x4*)&Gf[k*68 + c8*8]     = lo;
      *(f32x4*)&Gf[k*68 + c8*8 + 4] = hi;
    }
    // H0
    #pragma unroll
    for (int jj = 0; jj < 2; ++jj){
      int l2 = t + jj * 256; int k = l2 >> 4, oc = l2 & 15;
      float y = w0c[oc*3]*lcs[k][0] + w0c[oc*3+1]*lcs[k][1] + w0c[oc*3+2]*lcs[k][2] + b0c[oc];
      H0s[k][oc] = fmaxf(0.f, a0c[oc]*y + d0c[oc]);
    }
    __syncthreads();   // (C) Gf, H0 ready
    // H1
    #pragma unroll
    for (int jj = 0; jj < 2; ++jj){
      int l2 = t + jj * 256; int k = l2 >> 4, oc = l2 & 15;
      float y = b1c[oc];
      #pragma unroll
      for (int ic = 0; ic < 16; ++ic) y += w1c[oc][ic] * H0s[k][ic];
      H1s[k][oc] = fmaxf(0.f, a1c[oc]*y + d1c[oc]);
    }
    __syncthreads();   // (D) H1 ready
    // Gt transpose + Wt compute (both K-major bf16)
    {
      int i = t & 63, kb = (t >> 6) * 8;
      u16x8 gv;
      #pragma unroll
      for (int j = 0; j < 8; ++j) gv[j] = f2b(Gf[(kb + j)*68 + i]);
      *(u16x8*)&Gt[i*40 + kb] = gv;
      float wrow[16];
      #pragma unroll
      for (int ic = 0; ic < 16; ++ic) wrow[ic] = w2c[i][ic];
      float a2 = a2c[i], d2 = d2c[i], bb2 = b2c[i];
      u16x8 wv;
      #pragma unroll
      for (int j = 0; j < 8; ++j){
        const f32x4* hr = (const f32x4*)&H1s[kb + j][0];
        f32x4 h0v = hr[0], h1v = hr[1], h2v = hr[2], h3v = hr[3];
        float y = bb2;
        y += wrow[0]*h0v.x + wrow[1]*h0v.y + wrow[2]*h0v.z + wrow[3]*h0v.w;
        y += wrow[4]*h1v.x + wrow[5]*h1v.y + wrow[6]*h1v.z + wrow[7]*h1v.w;
        y += wrow[8]*h2v.x + wrow[9]*h2v.y + wrow[10]*h2v.z + wrow[11]*h2v.w;
        y += wrow[12]*h3v.x + wrow[13]*h3v.y + wrow[14]*h3v.z + wrow[15]*h3v.w;
        wv[j] = f2b(fmaxf(0.f, a2*y + d2));
      }
      *(u16x8*)&Wt[i*40 + kb] = wv;
    }
    __syncthreads();   // (E) Gt, Wt ready
    // MFMA: wave w -> m-tile w (np rows w*16..w*16+15), 4 n-tiles, K=32 in one mfma
    {
      s16x8 af = *(const s16x8*)&Gt[(w*16 + (l & 15))*40 + (l >> 4)*8];
      #pragma unroll
      for (int tn = 0; tn < 4; ++tn){
        s16x8 bfr = *(const s16x8*)&Wt[(tn*16 + (l & 15))*40 + (l >> 4)*8];
        f32x4 z = {0.f, 0.f, 0.f, 0.f};
        f32x4 d = __builtin_amdgcn_mfma_f32_16x16x32_bf16(af, bfr, z, 0, 0, 0);
        #pragma unroll
        for (int r = 0; r < 4; ++r)
          Cl[(w*16 + (l >> 4)*4 + r)*72 + tn*16 + (l & 15)] = f2b(d[r]);
      }
    }
    __syncthreads();   // (F) Cl ready
    // coalesced store + stats accumulation
    {
      int row = t >> 2, sg = t & 3;
      u16x8 c0 = *(const u16x8*)&Cl[row*72 + sg*16];
      u16x8 c1 = *(const u16x8*)&Cl[row*72 + sg*16 + 8];
      size_t gbase = (size_t)point * 4096 + row*64 + sg*16;
      *(u16x8*)(npw + gbase)     = c0;
      *(u16x8*)(npw + gbase + 8) = c1;
      #pragma unroll
      for (int j = 0; j < 8; ++j){ float v = bf(c0[j]); s[j]   += v; q[j]   += v*v; }
      #pragma unroll
      for (int j = 0; j < 8; ++j){ float v = bf(c1[j]); s[8+j] += v; q[8+j] += v*v; }
    }
  }
  float* slot = slotC + (size_t)(blockIdx.x & (NSLOT-1)) * 8192;
  int ch0 = (t >> 2)*64 + (t & 3)*16;
  #pragma unroll
  for (int j = 0; j < 16; ++j){
    atomicAdd(&slot[ch0 + j], s[j]);
    atomicAdd(&slot[4096 + ch0 + j], q[j]);
  }
}

// ---------------- K6b: reduce slots + finalize 4096-channel BN scale/shift ----------------
__global__ __launch_bounds__(256) void k_finC(const float* slotC, const float* gc, const float* bc,
                                              float* AC, float* DC){
  int ch = blockIdx.x * 256 + threadIdx.x;
  float s = 0.f, q = 0.f;
  #pragma unroll
  for (int sl = 0; sl < NSLOT; ++sl){
    s += slotC[(size_t)sl * 8192 + ch];
    q += slotC[(size_t)sl * 8192 + 4096 + ch];
  }
  float m = s * (1.f/16384.f);
  float v = q * (1.f/16384.f) - m*m;
  float a = gc[ch] * rsqrtf(v + EPSF);
  AC[ch] = a; DC[ch] = bc[ch] - m*a;
}

// ---------------- K7: MFMA GEMM [16384,4096]x[4096,64], fused bn+relu on A ----------------
__global__ __launch_bounds__(256) void k_linear(const u16* npw, const float* AC, const float* DC,
                                                const u16* lwbt, const float* lb, float* yw){
  __shared__ u16 Al[32*72];   // bf16, 32 rows x (64 k + pad)
  __shared__ u16 Bl[64*72];   // bf16, 64 n x (64 k + pad)
  int t = threadIdx.x;
  int w = t >> 6, l = t & 63;
  int rowbase = blockIdx.x * 32;
  int mt = w & 1, np2 = w >> 1;
  f32x4 acc0 = {0.f,0.f,0.f,0.f}, acc1 = acc0;
  for (int kb = 0; kb < 4096; kb += 64){
    __syncthreads();
    // stage A with fused bn+relu -> bf16
    {
      int r = t >> 3, c8 = t & 7;
      int kk = kb + c8*8;
      u16x8 u = *(const u16x8*)(npw + (size_t)(rowbase + r)*4096 + kk);
      f32x4 alo = *(const f32x4*)(AC + kk), ahi = *(const f32x4*)(AC + kk + 4);
      f32x4 dlo = *(const f32x4*)(DC + kk), dhi = *(const f32x4*)(DC + kk + 4);
      u16x8 o;
      o[0] = f2b(fmaxf(0.f, alo.x*bf(u[0]) + dlo.x));
      o[1] = f2b(fmaxf(0.f, alo.y*bf(u[1]) + dlo.y));
      o[2] = f2b(fmaxf(0.f, alo.z*bf(u[2]) + dlo.z));
      o[3] = f2b(fmaxf(0.f, alo.w*bf(u[3]) + dlo.w));
      o[4] = f2b(fmaxf(0.f, ahi.x*bf(u[4]) + dhi.x));
      o[5] = f2b(fmaxf(0.f, ahi.y*bf(u[5]) + dhi.y));
      o[6] = f2b(fmaxf(0.f, ahi.z*bf(u[6]) + dhi.z));
      o[7] = f2b(fmaxf(0.f, ahi.w*bf(u[7]) + dhi.w));
      *(u16x8*)&Al[r*72 + c8*8] = o;
    }
    // stage B (already bf16 o-major)
    #pragma unroll
    for (int jj = 0; jj < 2; ++jj){
      int n = (t >> 3) + jj*32, c8 = t & 7;
      u16x8 u = *(const u16x8*)(lwbt + (size_t)n*4096 + kb + c8*8);
      *(u16x8*)&Bl[n*72 + c8*8] = u;
    }
    __syncthreads();
    #pragma unroll
    for (int ks = 0; ks < 2; ++ks){
      s16x8 af  = *(const s16x8*)&Al[(mt*16 + (l & 15))*72 + ks*32 + (l >> 4)*8];
      s16x8 bf0 = *(const s16x8*)&Bl[((np2*2    )*16 + (l & 15))*72 + ks*32 + (l >> 4)*8];
      s16x8 bf1 = *(const s16x8*)&Bl[((np2*2 + 1)*16 + (l & 15))*72 + ks*32 + (l >> 4)*8];
      acc0 = __builtin_amdgcn_mfma_f32_16x16x32_bf16(af, bf0, acc0, 0, 0, 0);
      acc1 = __builtin_amdgcn_mfma_f32_16x16x32_bf16(af, bf1, acc1, 0, 0, 0);
    }
  }
  int col0 = np2*32 + (l & 15), col1 = col0 + 16;
  float lb0 = lb[col0], lb1 = lb[col1];
  #pragma unroll
  for (int r = 0; r < 4; ++r){
    int row = rowbase + mt*16 + (l >> 4)*4 + r;
    yw[(size_t)row*64 + col0] = acc0[r] + lb0;
    yw[(size_t)row*64 + col1] = acc1[r] + lb1;
  }
}

// ---------------- K8a: final-BN stats -> block partials ----------------
__global__ __launch_bounds__(256) void k_statL(const float* yw, float* PL){
  __shared__ float sh[4][128];
  int t = threadIdx.x;
  int o = t & 63;
  int w = t >> 6;
  int rg = blockIdx.x * 4 + w;
  float s = 0.f, q = 0.f;
  for (int r = rg * 64; r < rg * 64 + 64; ++r){
    float v = yw[(size_t)r * 64 + o];
    s += v; q += v*v;
  }
  sh[w][o] = s; sh[w][64+o] = q;
  __syncthreads();
  if (t < 128) PL[blockIdx.x*128 + t] = sh[0][t] + sh[1][t] + sh[2][t] + sh[3][t];
}

__global__ __launch_bounds__(128) void k_redL(const float* PL, float* SL){
  int t = threadIdx.x;
  float s = 0.f;
  for (int b = 0; b < 64; ++b) s += PL[b*128 + t];
  SL[t] = s;
}

__global__ __launch_bounds__(256) void k_final(const float* yw, const float* SL,
                                               const float* gl, const float* bl, float* out){
  int gid = blockIdx.x * 256 + threadIdx.x;
  int o = gid & 63;
  float m = SL[o] * (1.f/16384.f);
  float v = SL[64 + o] * (1.f/16384.f) - m*m;
  float a = gl[o] * rsqrtf(v + EPSF);
  float d = bl[o] - m*a;
  float y = fmaxf(0.f, a * yw[gid] + d);
  out[49152 + gid] = y;
}

extern "C" void kernel_launch(void* const* d_in, const int* in_sizes, int n_in,
                              void* d_out, int out_size, void* d_ws, size_t ws_size,
                              hipStream_t stream){
  (void)in_sizes; (void)n_in; (void)out_size; (void)ws_size;
  const float* xyz    = (const float*)d_in[0];
  const float* points = (const float*)d_in[1];
  const float* lc     = (const float*)d_in[2];
  const int*   nbrl   = (const int*)d_in[3];
  const int*   didx   = (const int*)d_in[4];
  const float* w0 = (const float*)d_in[5];
  const float* b0 = (const float*)d_in[6];
  const float* g0 = (const float*)d_in[7];
  const float* be0= (const float*)d_in[8];
  const float* w1 = (const float*)d_in[9];
  const float* b1 = (const float*)d_in[10];
  const float* g1 = (const float*)d_in[11];
  const float* be1= (const float*)d_in[12];
  const float* w2 = (const float*)d_in[13];
  const float* b2 = (const float*)d_in[14];
  const float* g2 = (const float*)d_in[15];
  const float* be2= (const float*)d_in[16];
  const float* gc = (const float*)d_in[17];
  const float* bc = (const float*)d_in[18];
  const float* lw = (const float*)d_in[19];
  const float* lb = (const float*)d_in[20];
  const float* gl = (const float*)d_in[21];
  const float* bl = (const float*)d_in[22];
  float* out = (float*)d_out;
  char* ws = (char*)d_ws;

  float* S0 = (float*)ws;            // 32     @0
  float* S1 = S0 + 32;               // 32
  float* S2 = S1 + 32;               // 128
  float* SL = S2 + 128;              // 128
  float* AC = SL + 128;              // 4096
  float* DC = AC + 4096;             // 4096
  float* P0 = DC + 4096;             // 8192
  float* P1 = P0 + 8192;             // 8192
  float* P2 = P1 + 8192;             // 32768
  float* PL = P2 + 32768;            // 8192
  float* slotC = PL + 8192;          // 16*8192 = 131072
  u16*  npw  = (u16*)(ws + 1048576);                        // 128 MB bf16
  float* yw  = (float*)(ws + 1048576 + 134217728);          // 4 MB f32
  u16*  lwbt = (u16*)(ws + 1048576 + 134217728 + 4194304);  // 512 KB bf16

  hipMemsetAsync(slotC, 0, NSLOT * 8192 * sizeof(float), stream);
  k_newxyz <<<64,   256, 0, stream>>>(xyz, didx, out);
  k_prep   <<<64,   256, 0, stream>>>(lw, lwbt);
  k_wn0    <<<256,  256, 0, stream>>>(lc, w0, b0, P0);
  k_redP   <<<1,    256, 0, stream>>>(P0, S0, 32);
  k_wn1    <<<256,  256, 0, stream>>>(lc, w0, b0, g0, be0, S0, w1, b1, P1);
  k_redP   <<<1,    256, 0, stream>>>(P1, S1, 32);
  k_wn2    <<<256,  256, 0, stream>>>(lc, w0, b0, g0, be0, S0, w1, b1, g1, be1, S1, w2, b2, P2);
  k_redP   <<<1,    256, 0, stream>>>(P2, S2, 128);
  k_main   <<<1024, 256, 0, stream>>>(lc, nbrl, points, xyz,
                                      w0, b0, g0, be0, S0,
                                      w1, b1, g1, be1, S1,
                                      w2, b2, g2, be2, S2,
                                      npw, slotC);
  k_finC   <<<16,   256, 0, stream>>>(slotC, gc, bc, AC, DC);
  k_linear <<<512,  256, 0, stream>>>(npw, AC, DC, lwbt, lb, yw);
  k_statL  <<<64,   256, 0, stream>>>(yw, PL);
  k_redL   <<<1,    128, 0, stream>>>(PL, SL);
  k_final  <<<4096, 256, 0, stream>>>(yw, SL, gl, bl, out);
}

// Round 6
// 434.675 us; speedup vs baseline: 1.9278x; 1.9278x over previous
//
#include <hip/hip_runtime.h>

#define BB 16
#define NN 4096
#define NPOINTS 1024
#define KK 32
#define NPTS (BB*NPOINTS)        // 16384
#define NWN  (BB*NPOINTS*KK)     // 524288
#define EPSF 1e-5f

typedef unsigned short u16;
typedef u16  u16x8 __attribute__((ext_vector_type(8)));
typedef short s16x8 __attribute__((ext_vector_type(8)));
typedef float f32x4 __attribute__((ext_vector_type(4)));

__device__ __forceinline__ float bf(u16 u){
  union { unsigned int i; float f; } v; v.i = ((unsigned int)u) << 16; return v.f;
}
__device__ __forceinline__ u16 f2b(float f){
  union { float ff; unsigned int i; } v; v.ff = f;
  unsigned int r = v.i + 0x7FFFu + ((v.i >> 16) & 1u);
  return (u16)(r >> 16);
}
__device__ __forceinline__ void wave_red2(float& s, float& q){
  #pragma unroll
  for (int m = 1; m < 64; m <<= 1){ s += __shfl_xor(s, m); q += __shfl_xor(q, m); }
}

// ---------------- K0: new_xyz gather (f32 copy) ----------------
__global__ __launch_bounds__(256) void k_newxyz(const float* xyz, const int* didx, float* out){
  int p = blockIdx.x * 256 + threadIdx.x;
  if (p >= NPTS) return;
  int b = p >> 10;
  int idx = didx[p];
  const float* src = xyz + ((size_t)(b * NN + idx)) * 3;
  float* dst = out + (size_t)p * 3;
  dst[0] = src[0]; dst[1] = src[1]; dst[2] = src[2];
}

// ---------------- k_prep: lwbt[o][ch] = bf16(lw[ch][o]) ----------------
__global__ __launch_bounds__(256) void k_prep(const float* lw, u16* lwbt){
  __shared__ float T[64][65];
  int t = threadIdx.x;
  int kb = blockIdx.x * 64;
  {
    int k = t >> 2, c4 = t & 3;
    #pragma unroll
    for (int j = 0; j < 4; ++j)
      *(f32x4*)&T[k][c4*16 + j*4] = *(const f32x4*)(lw + (size_t)(kb + k)*64 + c4*16 + j*4);
  }
  __syncthreads();
  {
    int n = t >> 2, k4 = t & 3;
    u16x8 o0, o1;
    #pragma unroll
    for (int j = 0; j < 8; ++j) o0[j] = f2b(T[k4*16 + j][n]);
    #pragma unroll
    for (int j = 0; j < 8; ++j) o1[j] = f2b(T[k4*16 + 8 + j][n]);
    *(u16x8*)(lwbt + (size_t)n*4096 + kb + k4*16)     = o0;
    *(u16x8*)(lwbt + (size_t)n*4096 + kb + k4*16 + 8) = o1;
  }
}

// ---------------- stats kernels ----------------
__global__ __launch_bounds__(256) void k_wn0(const float* lc, const float* w0, const float* b0, float* P0){
  __shared__ float w0c[48], b0c[16];
  __shared__ float shs[4][16], shq[4][16];
  int t = threadIdx.x;
  if (t < 48) w0c[t] = w0[t];
  if (t < 16) b0c[t] = b0[t];
  __syncthreads();
  float s[16], q[16];
  #pragma unroll
  for (int oc = 0; oc < 16; ++oc){ s[oc] = 0.f; q[oc] = 0.f; }
  size_t base = (size_t)blockIdx.x * 2048 + t;
  for (int i = 0; i < 8; ++i){
    size_t p = base + (size_t)i * 256;
    float x0 = lc[p*3+0], x1 = lc[p*3+1], x2 = lc[p*3+2];
    #pragma unroll
    for (int oc = 0; oc < 16; ++oc){
      float y = w0c[oc*3]*x0 + w0c[oc*3+1]*x1 + w0c[oc*3+2]*x2 + b0c[oc];
      s[oc] += y; q[oc] += y*y;
    }
  }
  int lane = t & 63, wid = t >> 6;
  #pragma unroll
  for (int oc = 0; oc < 16; ++oc){
    wave_red2(s[oc], q[oc]);
    if (lane == 0){ shs[wid][oc] = s[oc]; shq[wid][oc] = q[oc]; }
  }
  __syncthreads();
  if (t < 16){
    P0[blockIdx.x*32 + t]      = shs[0][t] + shs[1][t] + shs[2][t] + shs[3][t];
    P0[blockIdx.x*32 + 16 + t] = shq[0][t] + shq[1][t] + shq[2][t] + shq[3][t];
  }
}

__global__ __launch_bounds__(256) void k_wn1(const float* lc, const float* w0, const float* b0,
                                             const float* g0, const float* be0, const float* S0,
                                             const float* w1, const float* b1, float* P1){
  __shared__ float w0c[48], b0c[16], a0[16], d0[16], w1c[256], b1c[16];
  __shared__ float shs[4][16], shq[4][16];
  int t = threadIdx.x;
  if (t < 48) w0c[t] = w0[t];
  if (t < 16){
    b0c[t] = b0[t]; b1c[t] = b1[t];
    float m = S0[t] * (1.0f/NWN);
    float v = S0[16+t] * (1.0f/NWN) - m*m;
    float a = g0[t] * rsqrtf(v + EPSF);
    a0[t] = a; d0[t] = be0[t] - m*a;
  }
  w1c[t] = w1[t];
  __syncthreads();
  float s[16], q[16];
  #pragma unroll
  for (int oc = 0; oc < 16; ++oc){ s[oc] = 0.f; q[oc] = 0.f; }
  size_t base = (size_t)blockIdx.x * 2048 + t;
  for (int i = 0; i < 8; ++i){
    size_t p = base + (size_t)i * 256;
    float x0 = lc[p*3+0], x1 = lc[p*3+1], x2 = lc[p*3+2];
    float h0[16];
    #pragma unroll
    for (int oc = 0; oc < 16; ++oc){
      float y = w0c[oc*3]*x0 + w0c[oc*3+1]*x1 + w0c[oc*3+2]*x2 + b0c[oc];
      h0[oc] = fmaxf(0.f, a0[oc]*y + d0[oc]);
    }
    #pragma unroll
    for (int oc = 0; oc < 16; ++oc){
      float y = b1c[oc];
      #pragma unroll
      for (int ic = 0; ic < 16; ++ic) y += w1c[oc*16+ic]*h0[ic];
      s[oc] += y; q[oc] += y*y;
    }
  }
  int lane = t & 63, wid = t >> 6;
  #pragma unroll
  for (int oc = 0; oc < 16; ++oc){
    wave_red2(s[oc], q[oc]);
    if (lane == 0){ shs[wid][oc] = s[oc]; shq[wid][oc] = q[oc]; }
  }
  __syncthreads();
  if (t < 16){
    P1[blockIdx.x*32 + t]      = shs[0][t] + shs[1][t] + shs[2][t] + shs[3][t];
    P1[blockIdx.x*32 + 16 + t] = shq[0][t] + shq[1][t] + shq[2][t] + shq[3][t];
  }
}

__global__ __launch_bounds__(256) void k_wn2(const float* lc,
    const float* w0, const float* b0, const float* g0, const float* be0, const float* S0,
    const float* w1, const float* b1, const float* g1, const float* be1, const float* S1,
    const float* w2, const float* b2, float* P2){
  __shared__ float w0c[48], b0c[16], a0[16], d0[16];
  __shared__ float w1c[256], b1c[16], a1[16], d1[16];
  __shared__ float w2c[64][17], b2c[64];
  __shared__ float h0s[64][17], h1s[64][17];
  __shared__ float shs[4][64], shq[4][64];
  int t = threadIdx.x;
  if (t < 48) w0c[t] = w0[t];
  if (t < 16){
    b0c[t] = b0[t]; b1c[t] = b1[t];
    float m = S0[t] * (1.0f/NWN);
    float v = S0[16+t] * (1.0f/NWN) - m*m;
    float a = g0[t] * rsqrtf(v + EPSF);
    a0[t] = a; d0[t] = be0[t] - m*a;
    float m1 = S1[t] * (1.0f/NWN);
    float v1 = S1[16+t] * (1.0f/NWN) - m1*m1;
    float aa = g1[t] * rsqrtf(v1 + EPSF);
    a1[t] = aa; d1[t] = be1[t] - m1*aa;
  }
  w1c[t] = w1[t];
  for (int i = t; i < 1024; i += 256) w2c[i>>4][i&15] = w2[i];
  if (t < 64) b2c[t] = b2[t];
  __syncthreads();
  int oc = t & 63, w = t >> 6;
  float s = 0.f, q = 0.f;
  size_t cbase = (size_t)blockIdx.x * 2048;
  for (int ch = 0; ch < 32; ++ch){
    size_t pbase = cbase + ch * 64;
    __syncthreads();
    #pragma unroll
    for (int j = 0; j < 4; ++j){
      int l = t + j * 256;
      int k = l >> 4, c = l & 15;
      const float* xp = lc + (pbase + k) * 3;
      float y = w0c[c*3]*xp[0] + w0c[c*3+1]*xp[1] + w0c[c*3+2]*xp[2] + b0c[c];
      h0s[k][c] = fmaxf(0.f, a0[c]*y + d0[c]);
    }
    __syncthreads();
    #pragma unroll
    for (int j = 0; j < 4; ++j){
      int l = t + j * 256;
      int k = l >> 4, c = l & 15;
      float y = b1c[c];
      #pragma unroll
      for (int ic = 0; ic < 16; ++ic) y += w1c[c*16+ic] * h0s[k][ic];
      h1s[k][c] = fmaxf(0.f, a1[c]*y + d1[c]);
    }
    __syncthreads();
    #pragma unroll
    for (int kk = 0; kk < 16; ++kk){
      int k = w * 16 + kk;
      float y = b2c[oc];
      #pragma unroll
      for (int ic = 0; ic < 16; ++ic) y += w2c[oc][ic] * h1s[k][ic];
      s += y; q += y*y;
    }
  }
  shs[w][oc] = s; shq[w][oc] = q;
  __syncthreads();
  if (t < 64){
    P2[blockIdx.x*128 + t]      = shs[0][t] + shs[1][t] + shs[2][t] + shs[3][t];
    P2[blockIdx.x*128 + 64 + t] = shq[0][t] + shq[1][t] + shq[2][t] + shq[3][t];
  }
}

// ---------------- generic partial reduce ----------------
__global__ __launch_bounds__(256) void k_redP(const float* P, float* S, int nch){
  int t = threadIdx.x;
  if (t >= nch) return;
  float s = 0.f;
  for (int r = 0; r < 256; ++r) s += P[r*nch + t];
  S[t] = s;
}

// ---------------- K5: one point per block — gather + WeightNet + MFMA ----------------
__global__ __launch_bounds__(256) void k_main(const float* lcg, const int* nbrg,
    const float* points, const float* xyz,
    const float* w0, const float* b0, const float* g0, const float* be0, const float* S0,
    const float* w1, const float* b1, const float* g1, const float* be1, const float* S1,
    const float* w2, const float* b2, const float* g2, const float* be2, const float* S2,
    u16* npw){
  __shared__ u16   Gr[32*72];          // bf16 row-major: Gr[k][i], stride 72
  __shared__ u16   Wr[32*72];          // bf16 row-major: Wr[k][o], stride 72
  __shared__ float H0s[32][17];
  __shared__ float H1s[32][20];        // stride 20 -> 16B-aligned f32x4 rows
  __shared__ float lcs[32][4];
  __shared__ int   nbr[32];
  __shared__ float w0c[48], b0c[16], a0c[16], d0c[16];
  __shared__ float w1c[16][17], b1c[16], a1c[16], d1c[16];
  __shared__ float w2c[64][17], b2c[64], a2c[64], d2c[64];
  int t = threadIdx.x;
  int point = blockIdx.x;
  int bb = point >> 10;
  if (t < 48) w0c[t] = w0[t];
  if (t < 16){
    b0c[t] = b0[t]; b1c[t] = b1[t];
    float m = S0[t] * (1.0f/NWN);
    float v = S0[16+t] * (1.0f/NWN) - m*m;
    float a = g0[t] * rsqrtf(v + EPSF);
    a0c[t] = a; d0c[t] = be0[t] - m*a;
    float m1 = S1[t] * (1.0f/NWN);
    float v1 = S1[16+t] * (1.0f/NWN) - m1*m1;
    float aa = g1[t] * rsqrtf(v1 + EPSF);
    a1c[t] = aa; d1c[t] = be1[t] - m1*aa;
  }
  w1c[t>>4][t&15] = w1[t];
  for (int i = t; i < 1024; i += 256) w2c[i>>4][i&15] = w2[i];
  if (t < 64){
    b2c[t] = b2[t];
    float m = S2[t] * (1.0f/NWN);
    float v = S2[64+t] * (1.0f/NWN) - m*m;
    float a = g2[t] * rsqrtf(v + EPSF);
    a2c[t] = a; d2c[t] = be2[t] - m*a;
  }
  if (t < 32) nbr[t] = nbrg[(size_t)point * 32 + t];
  if (t < 96){ int k = t / 3, c = t % 3; lcs[k][c] = lcg[(size_t)point * 96 + t]; }
  __syncthreads();   // (A) weights + nbr + lcs ready

  // gather grouped -> Gr bf16 (coalesced row writes)
  {
    int k = t >> 3, c8 = t & 7;
    int n = nbr[k];
    const float* prow = points + (size_t)(bb * NN + n) * 61;
    const float* xr   = xyz    + (size_t)(bb * NN + n) * 3;
    u16x8 g;
    #pragma unroll
    for (int j = 0; j < 8; ++j){
      int c = c8 * 8 + j;
      g[j] = f2b((c < 61) ? prow[c] : xr[c - 61]);
    }
    *(u16x8*)&Gr[k*72 + c8*8] = g;
  }
  // H0
  #pragma unroll
  for (int jj = 0; jj < 2; ++jj){
    int l2 = t + jj * 256; int k = l2 >> 4, oc = l2 & 15;
    float y = w0c[oc*3]*lcs[k][0] + w0c[oc*3+1]*lcs[k][1] + w0c[oc*3+2]*lcs[k][2] + b0c[oc];
    H0s[k][oc] = fmaxf(0.f, a0c[oc]*y + d0c[oc]);
  }
  __syncthreads();   // (B) H0 ready
  // H1
  #pragma unroll
  for (int jj = 0; jj < 2; ++jj){
    int l2 = t + jj * 256; int k = l2 >> 4, oc = l2 & 15;
    float y = b1c[oc];
    #pragma unroll
    for (int ic = 0; ic < 16; ++ic) y += w1c[oc][ic] * H0s[k][ic];
    H1s[k][oc] = fmaxf(0.f, a1c[oc]*y + d1c[oc]);
  }
  __syncthreads();   // (C) H1 ready
  // W -> Wr (row-major k-major writes, conflict-light columns)
  {
    int o = t & 63, kb = (t >> 6) * 8;
    float wrow[16];
    #pragma unroll
    for (int ic = 0; ic < 16; ++ic) wrow[ic] = w2c[o][ic];
    float a2 = a2c[o], d2 = d2c[o], bb2 = b2c[o];
    #pragma unroll
    for (int j = 0; j < 8; ++j){
      const f32x4* hr = (const f32x4*)&H1s[kb + j][0];
      f32x4 h0v = hr[0], h1v = hr[1], h2v = hr[2], h3v = hr[3];
      float y = bb2;
      y += wrow[0]*h0v.x + wrow[1]*h0v.y + wrow[2]*h0v.z + wrow[3]*h0v.w;
      y += wrow[4]*h1v.x + wrow[5]*h1v.y + wrow[6]*h1v.z + wrow[7]*h1v.w;
      y += wrow[8]*h2v.x + wrow[9]*h2v.y + wrow[10]*h2v.z + wrow[11]*h2v.w;
      y += wrow[12]*h3v.x + wrow[13]*h3v.y + wrow[14]*h3v.z + wrow[15]*h3v.w;
      Wr[(kb + j)*72 + o] = f2b(fmaxf(0.f, a2*y + d2));
    }
  }
  __syncthreads();   // (D) Gr, Wr ready
  // MFMA: wave w owns o-tile w; all 4 i-tiles; direct global store
  {
    int w = t >> 6, l = t & 63;
    int li = l & 15, lk = (l >> 4) * 8, lr = (l >> 4) * 4;
    s16x8 bfrag;
    #pragma unroll
    for (int j = 0; j < 8; ++j) bfrag[j] = (short)Wr[(lk + j)*72 + w*16 + li];
    #pragma unroll
    for (int it = 0; it < 4; ++it){
      s16x8 afrag;
      #pragma unroll
      for (int j = 0; j < 8; ++j) afrag[j] = (short)Gr[(lk + j)*72 + it*16 + li];
      f32x4 z = {0.f, 0.f, 0.f, 0.f};
      f32x4 d = __builtin_amdgcn_mfma_f32_16x16x32_bf16(afrag, bfrag, z, 0, 0, 0);
      #pragma unroll
      for (int r = 0; r < 4; ++r)
        npw[(size_t)point*4096 + (size_t)(it*16 + lr + r)*64 + w*16 + li] = f2b(d[r]);
    }
  }
}

// ---------------- K5b: channel stats from npw (streaming, coalesced) ----------------
__global__ __launch_bounds__(256) void k_statC(const u16* npw, float* PC){
  int t = threadIdx.x;
  float s[16], q[16];
  #pragma unroll
  for (int j = 0; j < 16; ++j){ s[j] = 0.f; q[j] = 0.f; }
  size_t rowbase = (size_t)blockIdx.x * 64;
  for (int p = 0; p < 64; ++p){
    const u16* row = npw + (rowbase + p) * 4096 + t * 16;
    u16x8 a = *(const u16x8*)row;
    u16x8 b = *(const u16x8*)(row + 8);
    #pragma unroll
    for (int j = 0; j < 8; ++j){ float v = bf(a[j]); s[j]   += v; q[j]   += v*v; }
    #pragma unroll
    for (int j = 0; j < 8; ++j){ float v = bf(b[j]); s[8+j] += v; q[8+j] += v*v; }
  }
  float* dst = PC + (size_t)blockIdx.x * 8192 + t * 16;
  #pragma unroll
  for (int j = 0; j < 16; ++j){ dst[j] = s[j]; dst[4096 + j] = q[j]; }
}

// ---------------- K6b: reduce partials + finalize 4096-channel BN ----------------
__global__ __launch_bounds__(256) void k_finC(const float* PC, const float* gc, const float* bc,
                                              float* AC, float* DC){
  int ch = blockIdx.x * 256 + threadIdx.x;
  float s = 0.f, q = 0.f;
  for (int r = 0; r < 256; ++r){
    s += PC[(size_t)r * 8192 + ch];
    q += PC[(size_t)r * 8192 + 4096 + ch];
  }
  float m = s * (1.f/16384.f);
  float v = q * (1.f/16384.f) - m*m;
  float a = gc[ch] * rsqrtf(v + EPSF);
  AC[ch] = a; DC[ch] = bc[ch] - m*a;
}

// ---------------- K7: MFMA GEMM [16384,4096]x[4096,64], fused bn+relu on A ----------------
__global__ __launch_bounds__(256) void k_linear(const u16* npw, const float* AC, const float* DC,
                                                const u16* lwbt, const float* lb, float* yw){
  __shared__ u16 Al[32*72];
  __shared__ u16 Bl[64*72];
  int t = threadIdx.x;
  int w = t >> 6, l = t & 63;
  int rowbase = blockIdx.x * 32;
  int mt = w & 1, np2 = w >> 1;
  f32x4 acc0 = {0.f,0.f,0.f,0.f}, acc1 = acc0;
  for (int kb = 0; kb < 4096; kb += 64){
    __syncthreads();
    {
      int r = t >> 3, c8 = t & 7;
      int kk = kb + c8*8;
      u16x8 u = *(const u16x8*)(npw + (size_t)(rowbase + r)*4096 + kk);
      f32x4 alo = *(const f32x4*)(AC + kk), ahi = *(const f32x4*)(AC + kk + 4);
      f32x4 dlo = *(const f32x4*)(DC + kk), dhi = *(const f32x4*)(DC + kk + 4);
      u16x8 o;
      o[0] = f2b(fmaxf(0.f, alo.x*bf(u[0]) + dlo.x));
      o[1] = f2b(fmaxf(0.f, alo.y*bf(u[1]) + dlo.y));
      o[2] = f2b(fmaxf(0.f, alo.z*bf(u[2]) + dlo.z));
      o[3] = f2b(fmaxf(0.f, alo.w*bf(u[3]) + dlo.w));
      o[4] = f2b(fmaxf(0.f, ahi.x*bf(u[4]) + dhi.x));
      o[5] = f2b(fmaxf(0.f, ahi.y*bf(u[5]) + dhi.y));
      o[6] = f2b(fmaxf(0.f, ahi.z*bf(u[6]) + dhi.z));
      o[7] = f2b(fmaxf(0.f, ahi.w*bf(u[7]) + dhi.w));
      *(u16x8*)&Al[r*72 + c8*8] = o;
    }
    #pragma unroll
    for (int jj = 0; jj < 2; ++jj){
      int n = (t >> 3) + jj*32, c8 = t & 7;
      u16x8 u = *(const u16x8*)(lwbt + (size_t)n*4096 + kb + c8*8);
      *(u16x8*)&Bl[n*72 + c8*8] = u;
    }
    __syncthreads();
    #pragma unroll
    for (int ks = 0; ks < 2; ++ks){
      s16x8 af  = *(const s16x8*)&Al[(mt*16 + (l & 15))*72 + ks*32 + (l >> 4)*8];
      s16x8 bf0 = *(const s16x8*)&Bl[((np2*2    )*16 + (l & 15))*72 + ks*32 + (l >> 4)*8];
      s16x8 bf1 = *(const s16x8*)&Bl[((np2*2 + 1)*16 + (l & 15))*72 + ks*32 + (l >> 4)*8];
      acc0 = __builtin_amdgcn_mfma_f32_16x16x32_bf16(af, bf0, acc0, 0, 0, 0);
      acc1 = __builtin_amdgcn_mfma_f32_16x16x32_bf16(af, bf1, acc1, 0, 0, 0);
    }
  }
  int col0 = np2*32 + (l & 15), col1 = col0 + 16;
  float lb0 = lb[col0], lb1 = lb[col1];
  #pragma unroll
  for (int r = 0; r < 4; ++r){
    int row = rowbase + mt*16 + (l >> 4)*4 + r;
    yw[(size_t)row*64 + col0] = acc0[r] + lb0;
    yw[(size_t)row*64 + col1] = acc1[r] + lb1;
  }
}

// ---------------- K8a: final-BN stats -> block partials ----------------
__global__ __launch_bounds__(256) void k_statL(const float* yw, float* PL){
  __shared__ float sh[4][128];
  int t = threadIdx.x;
  int o = t & 63;
  int w = t >> 6;
  int rg = blockIdx.x * 4 + w;
  float s = 0.f, q = 0.f;
  for (int r = rg * 64; r < rg * 64 + 64; ++r){
    float v = yw[(size_t)r * 64 + o];
    s += v; q += v*v;
  }
  sh[w][o] = s; sh[w][64+o] = q;
  __syncthreads();
  if (t < 128) PL[blockIdx.x*128 + t] = sh[0][t] + sh[1][t] + sh[2][t] + sh[3][t];
}

__global__ __launch_bounds__(128) void k_redL(const float* PL, float* SL){
  int t = threadIdx.x;
  float s = 0.f;
  for (int b = 0; b < 64; ++b) s += PL[b*128 + t];
  SL[t] = s;
}

__global__ __launch_bounds__(256) void k_final(const float* yw, const float* SL,
                                               const float* gl, const float* bl, float* out){
  int gid = blockIdx.x * 256 + threadIdx.x;
  int o = gid & 63;
  float m = SL[o] * (1.f/16384.f);
  float v = SL[64 + o] * (1.f/16384.f) - m*m;
  float a = gl[o] * rsqrtf(v + EPSF);
  float d = bl[o] - m*a;
  float y = fmaxf(0.f, a * yw[gid] + d);
  out[49152 + gid] = y;
}

extern "C" void kernel_launch(void* const* d_in, const int* in_sizes, int n_in,
                              void* d_out, int out_size, void* d_ws, size_t ws_size,
                              hipStream_t stream){
  (void)in_sizes; (void)n_in; (void)out_size; (void)ws_size;
  const float* xyz    = (const float*)d_in[0];
  const float* points = (const float*)d_in[1];
  const float* lc     = (const float*)d_in[2];
  const int*   nbrl   = (const int*)d_in[3];
  const int*   didx   = (const int*)d_in[4];
  const float* w0 = (const float*)d_in[5];
  const float* b0 = (const float*)d_in[6];
  const float* g0 = (const float*)d_in[7];
  const float* be0= (const float*)d_in[8];
  const float* w1 = (const float*)d_in[9];
  const float* b1 = (const float*)d_in[10];
  const float* g1 = (const float*)d_in[11];
  const float* be1= (const float*)d_in[12];
  const float* w2 = (const float*)d_in[13];
  const float* b2 = (const float*)d_in[14];
  const float* g2 = (const float*)d_in[15];
  const float* be2= (const float*)d_in[16];
  const float* gc = (const float*)d_in[17];
  const float* bc = (const float*)d_in[18];
  const float* lw = (const float*)d_in[19];
  const float* lb = (const float*)d_in[20];
  const float* gl = (const float*)d_in[21];
  const float* bl = (const float*)d_in[22];
  float* out = (float*)d_out;
  char* ws = (char*)d_ws;

  float* S0 = (float*)ws;            // 32
  float* S1 = S0 + 32;               // 32
  float* S2 = S1 + 32;               // 128
  float* SL = S2 + 128;              // 128
  float* AC = SL + 128;              // 4096
  float* DC = AC + 4096;             // 4096
  float* P0 = DC + 4096;             // 8192
  float* P1 = P0 + 8192;             // 8192
  float* P2 = P1 + 8192;             // 32768
  float* PL = P2 + 32768;            // 8192
  float* PC = (float*)(ws + 1048576);                        // 256*8192 f32 = 8 MB
  u16*  npw  = (u16*)(ws + 1048576 + 8388608);               // 128 MB bf16
  float* yw  = (float*)(ws + 1048576 + 8388608 + 134217728); // 4 MB f32
  u16*  lwbt = (u16*)(ws + 1048576 + 8388608 + 134217728 + 4194304); // 512 KB

  k_newxyz <<<64,    256, 0, stream>>>(xyz, didx, out);
  k_prep   <<<64,    256, 0, stream>>>(lw, lwbt);
  k_wn0    <<<256,   256, 0, stream>>>(lc, w0, b0, P0);
  k_redP   <<<1,     256, 0, stream>>>(P0, S0, 32);
  k_wn1    <<<256,   256, 0, stream>>>(lc, w0, b0, g0, be0, S0, w1, b1, P1);
  k_redP   <<<1,     256, 0, stream>>>(P1, S1, 32);
  k_wn2    <<<256,   256, 0, stream>>>(lc, w0, b0, g0, be0, S0, w1, b1, g1, be1, S1, w2, b2, P2);
  k_redP   <<<1,     256, 0, stream>>>(P2, S2, 128);
  k_main   <<<16384, 256, 0, stream>>>(lc, nbrl, points, xyz,
                                       w0, b0, g0, be0, S0,
                                       w1, b1, g1, be1, S1,
                                       w2, b2, g2, be2, S2,
                                       npw);
  k_statC  <<<256,   256, 0, stream>>>(npw, PC);
  k_finC   <<<16,    256, 0, stream>>>(PC, gc, bc, AC, DC);
  k_linear <<<512,   256, 0, stream>>>(npw, AC, DC, lwbt, lb, yw);
  k_statL  <<<64,    256, 0, stream>>>(yw, PL);
  k_redL   <<<1,     128, 0, stream>>>(PL, SL);
  k_final  <<<4096,  256, 0, stream>>>(yw, SL, gl, bl, out);
}